// Round 15
// baseline (169.059 us; speedup 1.0000x reference)
//
#include <hip/hip_runtime.h>

// ---------------------------------------------------------------------------
// StaNet PAM — round 15: f16 datapath + interleaved-P packing + register lsum
// + 1024-WG channel-split projection. normconv byte-identical to r14.
//
// Workspace (float offsets), total 18.02 MB:
//   Qb   @ ush 0       : 262144 ush  [st][gp][ch] f16 (Q pre-scaled QMUL)
//   Kb   @ ush 262144  : 262144 ush  [st][gp][ch] f16
//   Vf   @ ush 524288  : 2097152 ush [st][blk][ch][slot] f16, slot-permuted:
//                        within each 64-key group, slot s holds key
//                        (s&1)*32 + (s>>1)  (matches interleaved P cols)
//   PART @ fl  1310720 : 6*524288 fl [slot][tile][qrow32][ch64]
//   LPART@ fl  4456448 : 6*8192 fl   [slot][gp]
// slots: 0,1 = st0 splits; 2,3 = st1 splits; 4 = st2; 5 = st3. tile == qt.
// MFMA 32x32x16 f16: A[m][k] m=lane&31,k=8*(lane>>5)+j; B[k][n] n=lane&31;
// C/D col=lane&31, row=(reg&3)+8*(reg>>2)+4*(lane>>5).
// ---------------------------------------------------------------------------

typedef _Float16 f16x8 __attribute__((ext_vector_type(8)));
typedef float f32x16 __attribute__((ext_vector_type(16)));

__device__ __forceinline__ unsigned short f2bf(float f){
    union{float f;unsigned int i;}v; v.f=f;
    unsigned int r = v.i + 0x7fffu + ((v.i>>16)&1u);
    return (unsigned short)(r>>16);
}
__device__ __forceinline__ unsigned short f2h(float f){
    union{_Float16 h; unsigned short u;}v; v.h = (_Float16)f; return v.u;
}
__device__ __forceinline__ unsigned pack2h(float a, float b){
    auto pk = __builtin_amdgcn_cvt_pkrtz(a, b);
    unsigned u; __builtin_memcpy(&u, &pk, 4); return u;
}
__device__ __forceinline__ float exp2fast(float x){ return __builtin_amdgcn_exp2f(x); }

#define QMUL 0.5100697233f   // 8^-0.5 * log2(e), folded into Q

// ---------------------------------------------------------------------------
// Kernel 1: fused Q/K/V projection. 1024 WGs (4 st x 128 chunks x 2 cgrp).
// Each WG: one 64-px x-tile, half the output channels; wave-uniform ranges:
//  cgrp0: w0 Q0-7+K0-1 | w1 K2-7+V0-3 | w2 V4-13 | w3 V14-23
//  cgrp1: w0 V24-33 | w1 V34-43 | w2 V44-53 | w3 V54-63
// V written in slot-permuted key order (see header).
// ---------------------------------------------------------------------------
__global__ __launch_bounds__(256) void proj_all_kernel(
    const float* __restrict__ x1, const float* __restrict__ x2,
    const float* __restrict__ Wq, const float* __restrict__ bq,
    const float* __restrict__ gq, const float* __restrict__ beq,
    const float* __restrict__ Wk, const float* __restrict__ bk,
    const float* __restrict__ gk, const float* __restrict__ bek,
    const float* __restrict__ Wv, const float* __restrict__ bv,
    unsigned short* __restrict__ Qb, unsigned short* __restrict__ Kb,
    unsigned short* __restrict__ Vf)
{
    __shared__ __align__(16) float xs[64][68];
    __shared__ __align__(16) unsigned vqk[64][8];       // [px][0-3 Q | 4-7 K]
    __shared__ __align__(16) unsigned short vv[64][64]; // [ch][key] (natural)

    const int wg = blockIdx.x, st = wg >> 8, rr = wg & 255;
    const int chunk = rr >> 1, cgrp = rr & 1;
    const int lgP = 13 - 2*st, Pm1 = (1<<lgP) - 1;
    const int hb = 6 - st, wlm = (1<<hb) - 1;
    const int t = threadIdx.x;
    const int gp0 = chunk*64;
    const int blk = gp0 >> lgP, p0 = gp0 & Pm1;
    const int si = blk >> st, sj = blk & ((1<<st)-1);
    const int hwbase = ((si<<hb)<<6) | (sj<<hb);

    for (int idx = t; idx < 4096; idx += 256) {
        int c = idx >> 6, g = idx & 63;
        int p = p0 + g, half = p & 1, pw = p >> 1;
        int hw = hwbase | ((pw>>hb)<<6) | (pw & wlm);
        xs[g][c] = (half ? x2 : x1)[c*4096 + hw];
    }
    __syncthreads();

    const int px = t & 63, wv = t >> 6;
    float xr[64];
    #pragma unroll
    for (int q4 = 0; q4 < 16; ++q4)
        *(float4*)&xr[q4*4] = *(const float4*)&xs[px][q4*4];

#define VRANGE(LO,HI)                                              \
    for (int ch = (LO); ch < (HI); ++ch) {                         \
        const float* wp = Wv + (st*64 + ch)*64;                    \
        float d = bv[st*64 + ch];                                  \
        _Pragma("unroll")                                          \
        for (int k = 0; k < 64; ++k) d += wp[k]*xr[k];             \
        vv[ch][px] = f2h(d);                                       \
    }
#define KPROJ(CH,DST)                                              \
    {   const float* wp = Wk + (st*8 + (CH))*64;                   \
        float d = 0.f;                                             \
        _Pragma("unroll")                                          \
        for (int k = 0; k < 64; ++k) d += wp[k]*xr[k];             \
        float gm = gk[st*8+(CH)];                                  \
        (DST) = gm*(d + bk[st*8+(CH)]) + bek[st*8+(CH)]; }

    if (cgrp == 0) {
        if (wv == 0) {
            float qv8[8];
            for (int ch = 0; ch < 8; ++ch) {
                const float* wp = Wq + (st*8 + ch)*64;
                float d = 0.f;
                #pragma unroll
                for (int k = 0; k < 64; ++k) d += wp[k]*xr[k];
                float gm = gq[st*8+ch];
                qv8[ch] = (gm*(d + bq[st*8+ch]) + beq[st*8+ch])*QMUL;
            }
            #pragma unroll
            for (int i = 0; i < 4; ++i) vqk[px][i] = pack2h(qv8[2*i], qv8[2*i+1]);
            float k0v, k1v; KPROJ(0, k0v) KPROJ(1, k1v)
            vqk[px][4] = pack2h(k0v, k1v);
        } else if (wv == 1) {
            float ka, kb2;
            KPROJ(2, ka) KPROJ(3, kb2) vqk[px][5] = pack2h(ka, kb2);
            KPROJ(4, ka) KPROJ(5, kb2) vqk[px][6] = pack2h(ka, kb2);
            KPROJ(6, ka) KPROJ(7, kb2) vqk[px][7] = pack2h(ka, kb2);
            VRANGE(0, 4)
        } else if (wv == 2) { VRANGE(4, 14) }
        else               { VRANGE(14, 24) }
    } else {
        if      (wv == 0) { VRANGE(24, 34) }
        else if (wv == 1) { VRANGE(34, 44) }
        else if (wv == 2) { VRANGE(44, 54) }
        else              { VRANGE(54, 64) }
    }
#undef VRANGE
#undef KPROJ
    __syncthreads();

    unsigned short* Vst = Vf + st*524288 + (blk << (lgP+6));
    if (cgrp == 0) {
        if (t < 64) {
            *(uint4*)(Qb + st*65536 + (gp0 + t)*8) = *(const uint4*)&vqk[t][0];
        } else if (t < 128) {
            int p2 = t - 64;
            *(uint4*)(Kb + st*65536 + (gp0 + p2)*8) = *(const uint4*)&vqk[p2][4];
        }
        if (t < 192) {                   // V ch 0-23, slot-permuted
            int ch = t >> 3, o = t & 7;
            unsigned short tmp[8];
            #pragma unroll
            for (int u = 0; u < 8; ++u) {
                int s = o*8 + u;
                tmp[u] = vv[ch][((s&1)<<5) | (s>>1)];
            }
            *(uint4*)(Vst + (ch << lgP) + p0 + o*8) = *(const uint4*)tmp;
        }
    } else {
        for (int task = t; task < 320; task += 256) {   // V ch 24-63
            int ch = 24 + (task >> 3), o = task & 7;
            unsigned short tmp[8];
            #pragma unroll
            for (int u = 0; u < 8; ++u) {
                int s = o*8 + u;
                tmp[u] = vv[ch][((s&1)<<5) | (s>>1)];
            }
            *(uint4*)(Vst + (ch << lgP) + p0 + o*8) = *(const uint4*)tmp;
        }
    }
}

// ---------------------------------------------------------------------------
// Kernel 2: barrier-free MFMA attention, f16. 1536 WGs x 256 threads.
// Same WG/slot map as r13/r14. P packed via cvt_pkrtz into interleaved cols
// (b32 LDS stores); V slot order matches; lsum accumulated in registers.
// ---------------------------------------------------------------------------
__global__ __launch_bounds__(256) void attn_kernel(
    const unsigned short* __restrict__ Qb, const unsigned short* __restrict__ Kb,
    const unsigned short* __restrict__ Vf,
    float* __restrict__ PART, float* __restrict__ LPART)
{
    __shared__ __align__(16) unsigned short Ps[4][2432];  // [q32][76]/wave

    const int wg = blockIdx.x;
    const int t = threadIdx.x, lane = t & 63, wv = t >> 6;
    const int l31 = lane & 31, lhi = lane >> 5;

    int st, qt, slot, kbase, nkw;
    if (wg < 512)       { st=0; qt=wg>>1;  slot=wg&1;
                          kbase=(wg&1)*4096 + wv*1024; nkw=1024; }
    else if (wg < 1024) { int r=wg-512;  st=1; qt=r>>1; slot=2+(r&1);
                          kbase=(r&1)*1024 + wv*256;  nkw=256; }
    else if (wg < 1280) { st=2; qt=wg-1024; slot=4; kbase=wv*128; nkw=128; }
    else                { st=3; qt=wg-1280; slot=5; kbase=wv*64;
                          nkw=(wv<2)?64:0; }

    const int lgP = 13 - 2*st, P = 1 << lgP;
    const int blk = qt >> (lgP - 5);
    const int q0  = (qt & ((P>>5)-1)) * 32;

    const unsigned short* Qg = Qb + st*65536 + blk*P*8;
    const unsigned short* Kg = Kb + st*65536 + blk*P*8;
    const unsigned short* Vg = Vf + st*524288 + blk*P*64;

    f16x8 qa;
    #pragma unroll
    for (int j = 0; j < 8; ++j) qa[j] = (_Float16)0.f;
    if (lane < 32) qa = *(const f16x8*)(Qg + (q0 + l31)*8);

    f32x16 acc0, acc1;
    #pragma unroll
    for (int r = 0; r < 16; ++r) { acc0[r] = 0.f; acc1[r] = 0.f; }
    float rowsum[16];
    #pragma unroll
    for (int r = 0; r < 16; ++r) rowsum[r] = 0.f;

    unsigned short* Pw = Ps[wv];
    unsigned* Pw32 = (unsigned*)Pw;
    for (int k0 = kbase; k0 < kbase + nkw; k0 += 64) {
        f16x8 kb0 = *(const f16x8*)(Kg + (k0 + l31)*8);
        f16x8 kb1 = *(const f16x8*)(Kg + (k0 + 32 + l31)*8);
        f32x16 S0, S1;
        #pragma unroll
        for (int r = 0; r < 16; ++r) { S0[r] = 0.f; S1[r] = 0.f; }
        S0 = __builtin_amdgcn_mfma_f32_32x32x16_f16(qa, kb0, S0, 0, 0, 0);
        S1 = __builtin_amdgcn_mfma_f32_32x32x16_f16(qa, kb1, S1, 0, 0, 0);

        // exp2 -> pkrtz pack -> one b32 LDS store per r (interleaved cols)
        #pragma unroll
        for (int r = 0; r < 16; ++r) {
            float p0 = exp2fast(S0[r]);
            float p1 = exp2fast(S1[r]);
            rowsum[r] += p0 + p1;
            int qrow = (r&3) + 8*(r>>2) + 4*lhi;
            Pw32[qrow*38 + l31] = pack2h(p0, p1);
        }

        // PV: A-frags contiguous in interleaved-pos space; V slot order matches
        #pragma unroll
        for (int kc = 0; kc < 4; ++kc) {
            f16x8 pa  = *(const f16x8*)(Pw + l31*76 + kc*16 + 8*lhi);
            const int ko = k0 + kc*16 + 8*lhi;
            f16x8 vb0 = *(const f16x8*)(Vg + l31*P + ko);
            f16x8 vb1 = *(const f16x8*)(Vg + (32 + l31)*P + ko);
            acc0 = __builtin_amdgcn_mfma_f32_32x32x16_f16(pa, vb0, acc0, 0, 0, 0);
            acc1 = __builtin_amdgcn_mfma_f32_32x32x16_f16(pa, vb1, acc1, 0, 0, 0);
        }
    }

    // per-wave lsum reduction (scratch = own Ps region; wave-local ordering)
    float* SC = (float*)Pw;
    #pragma unroll
    for (int r = 0; r < 16; ++r) {
        int qrow = (r&3) + 8*(r>>2) + 4*lhi;
        SC[qrow*33 + l31] = rowsum[r];
    }
    float lsum_reg = 0.f;
    if (lane < 32) {
        #pragma unroll 8
        for (int j = 0; j < 32; ++j) lsum_reg += SC[l31*33 + j];
    }

    // ---- intra-WG merge of the 4 wave partials (LDS tree, reusing Ps) ----
    float* B0 = (float*)&Ps[0][0];
    float* B1 = B0 + 2048;
    float* Lm = B0 + 4096;
    __syncthreads();
    if (wv == 0 || wv == 2) {
        float* B = (wv == 0) ? B0 : B1;
        #pragma unroll
        for (int r = 0; r < 16; ++r) {
            int qrow = (r&3) + 8*(r>>2) + 4*lhi;
            B[qrow*64 + l31]      = acc0[r];
            B[qrow*64 + 32 + l31] = acc1[r];
        }
        if (lane < 32) Lm[(wv>>1)*32 + l31] = lsum_reg;
    }
    __syncthreads();
    if (wv == 1 || wv == 3) {
        float* B = (wv == 1) ? B0 : B1;
        #pragma unroll
        for (int r = 0; r < 16; ++r) {
            int qrow = (r&3) + 8*(r>>2) + 4*lhi;
            B[qrow*64 + l31]      += acc0[r];
            B[qrow*64 + 32 + l31] += acc1[r];
        }
        if (lane < 32) Lm[(wv>>1)*32 + l31] += lsum_reg;
    }
    __syncthreads();

    float4* Pslab4 = (float4*)(PART + slot*524288 + qt*2048);
    const float4* B04 = (const float4*)B0;
    const float4* B14 = (const float4*)B1;
    #pragma unroll
    for (int r = 0; r < 2; ++r) {
        int idx = t + r*256;
        float4 a = B04[idx], b = B14[idx];
        Pslab4[idx] = float4{a.x+b.x, a.y+b.y, a.z+b.z, a.w+b.w};
    }
    if (t < 32)
        LPART[slot*8192 + qt*32 + t] = Lm[t] + Lm[32 + t];
}

// ---------------------------------------------------------------------------
// Kernel 3: normconv via MFMA (r14, unchanged).
// ---------------------------------------------------------------------------
typedef short bf16x8 __attribute__((ext_vector_type(8)));

__global__ __launch_bounds__(256) void normconv_kernel(
    const float* __restrict__ PART, const float* __restrict__ LPART,
    const float* __restrict__ Wo, float* __restrict__ out)
{
    __shared__ __align__(16) unsigned short csb[32][264];
    __shared__ __align__(16) unsigned short wof[16384];
    __shared__ float voutf[64][33];
    __shared__ float linv[4][32];
    __shared__ int gpar[4][32];
    const int t = threadIdx.x;
    const int px0 = blockIdx.x * 32;

    {
        int oc = t >> 2, d0 = (t & 3) * 64;
        for (int b = 0; b < 8; ++b) {
            int d = d0 + b*8;
            float4 w0 = *(const float4*)(Wo + oc*256 + d);
            float4 w1 = *(const float4*)(Wo + oc*256 + d + 4);
            unsigned short tmp[8];
            tmp[0]=f2bf(w0.x); tmp[1]=f2bf(w0.y); tmp[2]=f2bf(w0.z); tmp[3]=f2bf(w0.w);
            tmp[4]=f2bf(w1.x); tmp[5]=f2bf(w1.y); tmp[6]=f2bf(w1.z); tmp[7]=f2bf(w1.w);
            *(uint4*)&wof[(d>>3)*512 + oc*8] = *(const uint4*)tmp;
        }
    }
    if (t < 128) {
        const int s0tab[4] = {0,2,4,5};
        const int sctab[4] = {2,2,1,1};
        int stt = t >> 5, i = t & 31;
        int pix = px0 + i;
        int half = pix >> 12, hw = pix & 4095;
        int h = hw >> 6, w = hw & 63;
        int hb = 6 - stt, wlm = (1<<hb)-1;
        int si = h >> hb, sj = w >> hb, hi = h & wlm, wi = w & wlm;
        int blk = (si << stt) | sj;
        int p = (((hi << hb) | wi) << 1) | half;
        int gp = blk*(8192>>(2*stt)) + p;
        gpar[stt][i] = gp;
        int s0 = s0tab[stt];
        float l = LPART[s0*8192 + gp];
        if (sctab[stt] == 2) l += LPART[(s0+1)*8192 + gp];
        linv[stt][i] = 1.f / l;
    }
    __syncthreads();

    {
        const int s0tab[4] = {0,2,4,5};
        int gpx = t >> 3, cvg = (t & 7) * 8;
        for (int stt = 0; stt < 4; ++stt) {
            int gp = gpar[stt][gpx];
            const float* p = PART + s0tab[stt]*524288
                           + (gp>>5)*2048 + (gp&31)*64 + cvg;
            float4 a = *(const float4*)p;
            float4 b = *(const float4*)(p + 4);
            if (stt < 2) {
                float4 a2 = *(const float4*)(p + 524288);
                float4 b2 = *(const float4*)(p + 524288 + 4);
                a.x+=a2.x; a.y+=a2.y; a.z+=a2.z; a.w+=a2.w;
                b.x+=b2.x; b.y+=b2.y; b.z+=b2.z; b.w+=b2.w;
            }
            float li = linv[stt][gpx];
            unsigned short tmp[8];
            tmp[0]=f2bf(a.x*li); tmp[1]=f2bf(a.y*li); tmp[2]=f2bf(a.z*li); tmp[3]=f2bf(a.w*li);
            tmp[4]=f2bf(b.x*li); tmp[5]=f2bf(b.y*li); tmp[6]=f2bf(b.z*li); tmp[7]=f2bf(b.w*li);
            *(uint4*)&csb[gpx][stt*64 + cvg] = *(const uint4*)tmp;
        }
    }
    __syncthreads();

    const int lane = t & 63, wvv = t >> 6;
    const int l31 = lane & 31, lhi = lane >> 5;
    const int nh = wvv & 1, kh = wvv >> 1;
    f32x16 acc;
    #pragma unroll
    for (int r = 0; r < 16; ++r) acc[r] = 0.f;
    #pragma unroll
    for (int s = 0; s < 8; ++s) {
        int dg = kh*16 + s*2 + lhi;
        bf16x8 a = *(const bf16x8*)&csb[l31][kh*128 + s*16 + 8*lhi];
        bf16x8 b = *(const bf16x8*)&wof[dg*512 + (nh*32 + l31)*8];
        acc = __builtin_amdgcn_mfma_f32_32x32x16_bf16(a, b, acc, 0, 0, 0);
    }
    if (kh == 0) {
        #pragma unroll
        for (int r = 0; r < 16; ++r)
            voutf[nh*32 + l31][(r&3) + 8*(r>>2) + 4*lhi] = acc[r];
    }
    __syncthreads();
    if (kh == 1) {
        #pragma unroll
        for (int r = 0; r < 16; ++r)
            voutf[nh*32 + l31][(r&3) + 8*(r>>2) + 4*lhi] += acc[r];
    }
    __syncthreads();

    const int half = px0 >> 12, hw0 = px0 & 4095;
    float* obase = out + half*262144 + hw0;
    #pragma unroll
    for (int r = 0; r < 8; ++r) {
        int idx = t + r*256;
        int oc = idx >> 5, pxi = idx & 31;
        obase[oc*4096 + pxi] = voutf[oc][pxi];
    }
}

// ---------------------------------------------------------------------------
extern "C" void kernel_launch(void* const* d_in, const int* in_sizes, int n_in,
                              void* d_out, int out_size, void* d_ws, size_t ws_size,
                              hipStream_t stream)
{
    (void)out_size; (void)ws_size;
    const float *x1, *x2, *Wq, *bq, *gq, *beq, *Wk, *bk, *gk, *bek, *Wv, *bv, *Wo;

    if (n_in >= 13 && in_sizes[0] == 2048) {       // sorted-key order (insurance)
        Wk  = (const float*)d_in[0];  Wo  = (const float*)d_in[1];
        Wq  = (const float*)d_in[2];  Wv  = (const float*)d_in[3];
        bek = (const float*)d_in[4];  beq = (const float*)d_in[5];
        bk  = (const float*)d_in[6];  bq  = (const float*)d_in[7];
        bv  = (const float*)d_in[8];  gk  = (const float*)d_in[9];
        gq  = (const float*)d_in[10];
        x1  = (const float*)d_in[11]; x2  = (const float*)d_in[12];
    } else {                                        // insertion order (proven)
        x1  = (const float*)d_in[0];  x2  = (const float*)d_in[1];
        Wq  = (const float*)d_in[2];  bq  = (const float*)d_in[3];
        gq  = (const float*)d_in[4];  beq = (const float*)d_in[5];
        Wk  = (const float*)d_in[6];  bk  = (const float*)d_in[7];
        gk  = (const float*)d_in[8];  bek = (const float*)d_in[9];
        Wv  = (const float*)d_in[10]; bv  = (const float*)d_in[11];
        Wo  = (const float*)d_in[12];
    }

    unsigned short* Qb = (unsigned short*)d_ws;     // 262144 ush
    unsigned short* Kb = Qb + 262144;               // 262144 ush
    unsigned short* Vf = Kb + 262144;               // 2097152 ush
    float* PART  = (float*)d_ws + 1310720;          // 3145728 fl
    float* LPART = PART + 3145728;                  // 49152 fl

    proj_all_kernel<<<1024, 256, 0, stream>>>(x1,x2,Wq,bq,gq,beq,Wk,bk,gk,bek,Wv,bv,Qb,Kb,Vf);
    attn_kernel<<<1536, 256, 0, stream>>>(Qb,Kb,Vf,PART,LPART);
    normconv_kernel<<<256, 256, 0, stream>>>(PART, LPART, Wo, (float*)d_out);
}

// Round 16
// 156.943 us; speedup vs baseline: 1.0772x; 1.0772x over previous
//
#include <hip/hip_runtime.h>

// ---------------------------------------------------------------------------
// StaNet PAM — round 16: r15 + readfirstlane-scalarized projection weights.
// LLVM treats (threadIdx>>6)-derived values as divergent, so r14/r15's
// "wave-uniform" weight pointers compiled to per-lane VMEM loads (the hidden
// ~tens-of-us sink). rfl() forces SGPR weights -> s_load + SGPR-operand FMA.
// attn_kernel identical to r15; normconv identical to r14.
//
// Workspace (float offsets), total 18.02 MB:
//   Qb   @ ush 0       : 262144 ush  [st][gp][ch] f16 (Q pre-scaled QMUL)
//   Kb   @ ush 262144  : 262144 ush  [st][gp][ch] f16
//   Vf   @ ush 524288  : 2097152 ush [st][blk][ch][slot] f16, slot-permuted:
//                        slot s holds key (s&1)*32 + (s>>1) of its 64-group
//   PART @ fl  1310720 : 6*524288 fl [slot][tile][qrow32][ch64]
//   LPART@ fl  4456448 : 6*8192 fl   [slot][gp]
// slots: 0,1 = st0 splits; 2,3 = st1 splits; 4 = st2; 5 = st3. tile == qt.
// MFMA 32x32x16: A[m][k] m=lane&31,k=8*(lane>>5)+j; B[k][n] n=lane&31;
// C/D col=lane&31, row=(reg&3)+8*(reg>>2)+4*(lane>>5).
// ---------------------------------------------------------------------------

typedef _Float16 f16x8 __attribute__((ext_vector_type(8)));
typedef float f32x16 __attribute__((ext_vector_type(16)));
typedef short bf16x8 __attribute__((ext_vector_type(8)));

__device__ __forceinline__ unsigned short f2bf(float f){
    union{float f;unsigned int i;}v; v.f=f;
    unsigned int r = v.i + 0x7fffu + ((v.i>>16)&1u);
    return (unsigned short)(r>>16);
}
__device__ __forceinline__ unsigned short f2h(float f){
    union{_Float16 h; unsigned short u;}v; v.h = (_Float16)f; return v.u;
}
__device__ __forceinline__ unsigned pack2h(float a, float b){
    auto pk = __builtin_amdgcn_cvt_pkrtz(a, b);
    unsigned u; __builtin_memcpy(&u, &pk, 4); return u;
}
__device__ __forceinline__ float exp2fast(float x){ return __builtin_amdgcn_exp2f(x); }
// force wave-uniform value into an SGPR (value IS uniform in the wave)
__device__ __forceinline__ int rfl(int x){ return __builtin_amdgcn_readfirstlane(x); }

#define QMUL 0.5100697233f   // 8^-0.5 * log2(e), folded into Q

// ---------------------------------------------------------------------------
// Kernel 1: fused Q/K/V projection. 1024 WGs (4 st x 128 chunks x 2 cgrp).
// Channel ranges per wave; ALL weight/bias indices scalarized via rfl().
//  cgrp0: w0 Q0-7+K0-1 | w1 K2-7+V0-3 | w2 V4-13 | w3 V14-23
//  cgrp1: w0 V24-33 | w1 V34-43 | w2 V44-53 | w3 V54-63
// ---------------------------------------------------------------------------
__global__ __launch_bounds__(256) void proj_all_kernel(
    const float* __restrict__ x1, const float* __restrict__ x2,
    const float* __restrict__ Wq, const float* __restrict__ bq,
    const float* __restrict__ gq, const float* __restrict__ beq,
    const float* __restrict__ Wk, const float* __restrict__ bk,
    const float* __restrict__ gk, const float* __restrict__ bek,
    const float* __restrict__ Wv, const float* __restrict__ bv,
    unsigned short* __restrict__ Qb, unsigned short* __restrict__ Kb,
    unsigned short* __restrict__ Vf)
{
    __shared__ __align__(16) float xs[64][68];
    __shared__ __align__(16) unsigned vqk[64][8];       // [px][0-3 Q | 4-7 K]
    __shared__ __align__(16) unsigned short vv[64][64]; // [ch][key] (natural)

    const int wg = blockIdx.x, st = wg >> 8, rr = wg & 255;
    const int chunk = rr >> 1, cgrp = rr & 1;
    const int lgP = 13 - 2*st, Pm1 = (1<<lgP) - 1;
    const int hb = 6 - st, wlm = (1<<hb) - 1;
    const int t = threadIdx.x;
    const int gp0 = chunk*64;
    const int blk = gp0 >> lgP, p0 = gp0 & Pm1;
    const int si = blk >> st, sj = blk & ((1<<st)-1);
    const int hwbase = ((si<<hb)<<6) | (sj<<hb);

    for (int idx = t; idx < 4096; idx += 256) {
        int c = idx >> 6, g = idx & 63;
        int p = p0 + g, half = p & 1, pw = p >> 1;
        int hw = hwbase | ((pw>>hb)<<6) | (pw & wlm);
        xs[g][c] = (half ? x2 : x1)[c*4096 + hw];
    }
    __syncthreads();

    const int px = t & 63, wv = t >> 6;
    float xr[64];
    #pragma unroll
    for (int q4 = 0; q4 < 16; ++q4)
        *(float4*)&xr[q4*4] = *(const float4*)&xs[px][q4*4];

#define VRANGE(LO,HI)                                              \
    for (int ch = (LO); ch < (HI); ++ch) {                         \
        const int cu = rfl(st*64 + ch);                            \
        const float* wp = Wv + cu*64;                              \
        float d = bv[cu];                                          \
        _Pragma("unroll")                                          \
        for (int k = 0; k < 64; ++k) d += wp[k]*xr[k];             \
        vv[ch][px] = f2h(d);                                       \
    }
#define KPROJ(CH,DST)                                              \
    {   const int cu = rfl(st*8 + (CH));                           \
        const float* wp = Wk + cu*64;                              \
        float d = 0.f;                                             \
        _Pragma("unroll")                                          \
        for (int k = 0; k < 64; ++k) d += wp[k]*xr[k];             \
        float gm = gk[cu];                                         \
        (DST) = gm*(d + bk[cu]) + bek[cu]; }

    if (cgrp == 0) {
        if (wv == 0) {
            float qv8[8];
            for (int ch = 0; ch < 8; ++ch) {
                const int cu = rfl(st*8 + ch);
                const float* wp = Wq + cu*64;
                float d = 0.f;
                #pragma unroll
                for (int k = 0; k < 64; ++k) d += wp[k]*xr[k];
                float gm = gq[cu];
                qv8[ch] = (gm*(d + bq[cu]) + beq[cu])*QMUL;
            }
            #pragma unroll
            for (int i = 0; i < 4; ++i) vqk[px][i] = pack2h(qv8[2*i], qv8[2*i+1]);
            float k0v, k1v; KPROJ(0, k0v) KPROJ(1, k1v)
            vqk[px][4] = pack2h(k0v, k1v);
        } else if (wv == 1) {
            float ka, kb2;
            KPROJ(2, ka) KPROJ(3, kb2) vqk[px][5] = pack2h(ka, kb2);
            KPROJ(4, ka) KPROJ(5, kb2) vqk[px][6] = pack2h(ka, kb2);
            KPROJ(6, ka) KPROJ(7, kb2) vqk[px][7] = pack2h(ka, kb2);
            VRANGE(0, 4)
        } else if (wv == 2) { VRANGE(4, 14) }
        else               { VRANGE(14, 24) }
    } else {
        if      (wv == 0) { VRANGE(24, 34) }
        else if (wv == 1) { VRANGE(34, 44) }
        else if (wv == 2) { VRANGE(44, 54) }
        else              { VRANGE(54, 64) }
    }
#undef VRANGE
#undef KPROJ
    __syncthreads();

    unsigned short* Vst = Vf + st*524288 + (blk << (lgP+6));
    if (cgrp == 0) {
        if (t < 64) {
            *(uint4*)(Qb + st*65536 + (gp0 + t)*8) = *(const uint4*)&vqk[t][0];
        } else if (t < 128) {
            int p2 = t - 64;
            *(uint4*)(Kb + st*65536 + (gp0 + p2)*8) = *(const uint4*)&vqk[p2][4];
        }
        if (t < 192) {                   // V ch 0-23, slot-permuted
            int ch = t >> 3, o = t & 7;
            unsigned short tmp[8];
            #pragma unroll
            for (int u = 0; u < 8; ++u) {
                int s = o*8 + u;
                tmp[u] = vv[ch][((s&1)<<5) | (s>>1)];
            }
            *(uint4*)(Vst + (ch << lgP) + p0 + o*8) = *(const uint4*)tmp;
        }
    } else {
        for (int task = t; task < 320; task += 256) {   // V ch 24-63
            int ch = 24 + (task >> 3), o = task & 7;
            unsigned short tmp[8];
            #pragma unroll
            for (int u = 0; u < 8; ++u) {
                int s = o*8 + u;
                tmp[u] = vv[ch][((s&1)<<5) | (s>>1)];
            }
            *(uint4*)(Vst + (ch << lgP) + p0 + o*8) = *(const uint4*)tmp;
        }
    }
}

// ---------------------------------------------------------------------------
// Kernel 2: barrier-free MFMA attention, f16. 1536 WGs x 256 threads. (r15)
// ---------------------------------------------------------------------------
__global__ __launch_bounds__(256) void attn_kernel(
    const unsigned short* __restrict__ Qb, const unsigned short* __restrict__ Kb,
    const unsigned short* __restrict__ Vf,
    float* __restrict__ PART, float* __restrict__ LPART)
{
    __shared__ __align__(16) unsigned short Ps[4][2432];  // [q32][76]/wave

    const int wg = blockIdx.x;
    const int t = threadIdx.x, lane = t & 63, wv = t >> 6;
    const int l31 = lane & 31, lhi = lane >> 5;

    int st, qt, slot, kbase, nkw;
    if (wg < 512)       { st=0; qt=wg>>1;  slot=wg&1;
                          kbase=(wg&1)*4096 + wv*1024; nkw=1024; }
    else if (wg < 1024) { int r=wg-512;  st=1; qt=r>>1; slot=2+(r&1);
                          kbase=(r&1)*1024 + wv*256;  nkw=256; }
    else if (wg < 1280) { st=2; qt=wg-1024; slot=4; kbase=wv*128; nkw=128; }
    else                { st=3; qt=wg-1280; slot=5; kbase=wv*64;
                          nkw=(wv<2)?64:0; }

    const int lgP = 13 - 2*st, P = 1 << lgP;
    const int blk = qt >> (lgP - 5);
    const int q0  = (qt & ((P>>5)-1)) * 32;

    const unsigned short* Qg = Qb + st*65536 + blk*P*8;
    const unsigned short* Kg = Kb + st*65536 + blk*P*8;
    const unsigned short* Vg = Vf + st*524288 + blk*P*64;

    f16x8 qa;
    #pragma unroll
    for (int j = 0; j < 8; ++j) qa[j] = (_Float16)0.f;
    if (lane < 32) qa = *(const f16x8*)(Qg + (q0 + l31)*8);

    f32x16 acc0, acc1;
    #pragma unroll
    for (int r = 0; r < 16; ++r) { acc0[r] = 0.f; acc1[r] = 0.f; }
    float rowsum[16];
    #pragma unroll
    for (int r = 0; r < 16; ++r) rowsum[r] = 0.f;

    unsigned short* Pw = Ps[wv];
    unsigned* Pw32 = (unsigned*)Pw;
    for (int k0 = kbase; k0 < kbase + nkw; k0 += 64) {
        f16x8 kb0 = *(const f16x8*)(Kg + (k0 + l31)*8);
        f16x8 kb1 = *(const f16x8*)(Kg + (k0 + 32 + l31)*8);
        f32x16 S0, S1;
        #pragma unroll
        for (int r = 0; r < 16; ++r) { S0[r] = 0.f; S1[r] = 0.f; }
        S0 = __builtin_amdgcn_mfma_f32_32x32x16_f16(qa, kb0, S0, 0, 0, 0);
        S1 = __builtin_amdgcn_mfma_f32_32x32x16_f16(qa, kb1, S1, 0, 0, 0);

        #pragma unroll
        for (int r = 0; r < 16; ++r) {
            float p0 = exp2fast(S0[r]);
            float p1 = exp2fast(S1[r]);
            rowsum[r] += p0 + p1;
            int qrow = (r&3) + 8*(r>>2) + 4*lhi;
            Pw32[qrow*38 + l31] = pack2h(p0, p1);
        }

        #pragma unroll
        for (int kc = 0; kc < 4; ++kc) {
            f16x8 pa  = *(const f16x8*)(Pw + l31*76 + kc*16 + 8*lhi);
            const int ko = k0 + kc*16 + 8*lhi;
            f16x8 vb0 = *(const f16x8*)(Vg + l31*P + ko);
            f16x8 vb1 = *(const f16x8*)(Vg + (32 + l31)*P + ko);
            acc0 = __builtin_amdgcn_mfma_f32_32x32x16_f16(pa, vb0, acc0, 0, 0, 0);
            acc1 = __builtin_amdgcn_mfma_f32_32x32x16_f16(pa, vb1, acc1, 0, 0, 0);
        }
    }

    float* SC = (float*)Pw;
    #pragma unroll
    for (int r = 0; r < 16; ++r) {
        int qrow = (r&3) + 8*(r>>2) + 4*lhi;
        SC[qrow*33 + l31] = rowsum[r];
    }
    float lsum_reg = 0.f;
    if (lane < 32) {
        #pragma unroll 8
        for (int j = 0; j < 32; ++j) lsum_reg += SC[l31*33 + j];
    }

    float* B0 = (float*)&Ps[0][0];
    float* B1 = B0 + 2048;
    float* Lm = B0 + 4096;
    __syncthreads();
    if (wv == 0 || wv == 2) {
        float* B = (wv == 0) ? B0 : B1;
        #pragma unroll
        for (int r = 0; r < 16; ++r) {
            int qrow = (r&3) + 8*(r>>2) + 4*lhi;
            B[qrow*64 + l31]      = acc0[r];
            B[qrow*64 + 32 + l31] = acc1[r];
        }
        if (lane < 32) Lm[(wv>>1)*32 + l31] = lsum_reg;
    }
    __syncthreads();
    if (wv == 1 || wv == 3) {
        float* B = (wv == 1) ? B0 : B1;
        #pragma unroll
        for (int r = 0; r < 16; ++r) {
            int qrow = (r&3) + 8*(r>>2) + 4*lhi;
            B[qrow*64 + l31]      += acc0[r];
            B[qrow*64 + 32 + l31] += acc1[r];
        }
        if (lane < 32) Lm[(wv>>1)*32 + l31] += lsum_reg;
    }
    __syncthreads();

    float4* Pslab4 = (float4*)(PART + slot*524288 + qt*2048);
    const float4* B04 = (const float4*)B0;
    const float4* B14 = (const float4*)B1;
    #pragma unroll
    for (int r = 0; r < 2; ++r) {
        int idx = t + r*256;
        float4 a = B04[idx], b = B14[idx];
        Pslab4[idx] = float4{a.x+b.x, a.y+b.y, a.z+b.z, a.w+b.w};
    }
    if (t < 32)
        LPART[slot*8192 + qt*32 + t] = Lm[t] + Lm[32 + t];
}

// ---------------------------------------------------------------------------
// Kernel 3: normconv via MFMA (r14, unchanged).
// ---------------------------------------------------------------------------
__global__ __launch_bounds__(256) void normconv_kernel(
    const float* __restrict__ PART, const float* __restrict__ LPART,
    const float* __restrict__ Wo, float* __restrict__ out)
{
    __shared__ __align__(16) unsigned short csb[32][264];
    __shared__ __align__(16) unsigned short wof[16384];
    __shared__ float voutf[64][33];
    __shared__ float linv[4][32];
    __shared__ int gpar[4][32];
    const int t = threadIdx.x;
    const int px0 = blockIdx.x * 32;

    {
        int oc = t >> 2, d0 = (t & 3) * 64;
        for (int b = 0; b < 8; ++b) {
            int d = d0 + b*8;
            float4 w0 = *(const float4*)(Wo + oc*256 + d);
            float4 w1 = *(const float4*)(Wo + oc*256 + d + 4);
            unsigned short tmp[8];
            tmp[0]=f2bf(w0.x); tmp[1]=f2bf(w0.y); tmp[2]=f2bf(w0.z); tmp[3]=f2bf(w0.w);
            tmp[4]=f2bf(w1.x); tmp[5]=f2bf(w1.y); tmp[6]=f2bf(w1.z); tmp[7]=f2bf(w1.w);
            *(uint4*)&wof[(d>>3)*512 + oc*8] = *(const uint4*)tmp;
        }
    }
    if (t < 128) {
        const int s0tab[4] = {0,2,4,5};
        const int sctab[4] = {2,2,1,1};
        int stt = t >> 5, i = t & 31;
        int pix = px0 + i;
        int half = pix >> 12, hw = pix & 4095;
        int h = hw >> 6, w = hw & 63;
        int hb = 6 - stt, wlm = (1<<hb)-1;
        int si = h >> hb, sj = w >> hb, hi = h & wlm, wi = w & wlm;
        int blk = (si << stt) | sj;
        int p = (((hi << hb) | wi) << 1) | half;
        int gp = blk*(8192>>(2*stt)) + p;
        gpar[stt][i] = gp;
        int s0 = s0tab[stt];
        float l = LPART[s0*8192 + gp];
        if (sctab[stt] == 2) l += LPART[(s0+1)*8192 + gp];
        linv[stt][i] = 1.f / l;
    }
    __syncthreads();

    {
        const int s0tab[4] = {0,2,4,5};
        int gpx = t >> 3, cvg = (t & 7) * 8;
        for (int stt = 0; stt < 4; ++stt) {
            int gp = gpar[stt][gpx];
            const float* p = PART + s0tab[stt]*524288
                           + (gp>>5)*2048 + (gp&31)*64 + cvg;
            float4 a = *(const float4*)p;
            float4 b = *(const float4*)(p + 4);
            if (stt < 2) {
                float4 a2 = *(const float4*)(p + 524288);
                float4 b2 = *(const float4*)(p + 524288 + 4);
                a.x+=a2.x; a.y+=a2.y; a.z+=a2.z; a.w+=a2.w;
                b.x+=b2.x; b.y+=b2.y; b.z+=b2.z; b.w+=b2.w;
            }
            float li = linv[stt][gpx];
            unsigned short tmp[8];
            tmp[0]=f2bf(a.x*li); tmp[1]=f2bf(a.y*li); tmp[2]=f2bf(a.z*li); tmp[3]=f2bf(a.w*li);
            tmp[4]=f2bf(b.x*li); tmp[5]=f2bf(b.y*li); tmp[6]=f2bf(b.z*li); tmp[7]=f2bf(b.w*li);
            *(uint4*)&csb[gpx][stt*64 + cvg] = *(const uint4*)tmp;
        }
    }
    __syncthreads();

    const int lane = t & 63, wvv = t >> 6;
    const int l31 = lane & 31, lhi = lane >> 5;
    const int nh = wvv & 1, kh = wvv >> 1;
    f32x16 acc;
    #pragma unroll
    for (int r = 0; r < 16; ++r) acc[r] = 0.f;
    #pragma unroll
    for (int s = 0; s < 8; ++s) {
        int dg = kh*16 + s*2 + lhi;
        bf16x8 a = *(const bf16x8*)&csb[l31][kh*128 + s*16 + 8*lhi];
        bf16x8 b = *(const bf16x8*)&wof[dg*512 + (nh*32 + l31)*8];
        acc = __builtin_amdgcn_mfma_f32_32x32x16_bf16(a, b, acc, 0, 0, 0);
    }
    if (kh == 0) {
        #pragma unroll
        for (int r = 0; r < 16; ++r)
            voutf[nh*32 + l31][(r&3) + 8*(r>>2) + 4*lhi] = acc[r];
    }
    __syncthreads();
    if (kh == 1) {
        #pragma unroll
        for (int r = 0; r < 16; ++r)
            voutf[nh*32 + l31][(r&3) + 8*(r>>2) + 4*lhi] += acc[r];
    }
    __syncthreads();

    const int half = px0 >> 12, hw0 = px0 & 4095;
    float* obase = out + half*262144 + hw0;
    #pragma unroll
    for (int r = 0; r < 8; ++r) {
        int idx = t + r*256;
        int oc = idx >> 5, pxi = idx & 31;
        obase[oc*4096 + pxi] = voutf[oc][pxi];
    }
}

// ---------------------------------------------------------------------------
extern "C" void kernel_launch(void* const* d_in, const int* in_sizes, int n_in,
                              void* d_out, int out_size, void* d_ws, size_t ws_size,
                              hipStream_t stream)
{
    (void)out_size; (void)ws_size;
    const float *x1, *x2, *Wq, *bq, *gq, *beq, *Wk, *bk, *gk, *bek, *Wv, *bv, *Wo;

    if (n_in >= 13 && in_sizes[0] == 2048) {       // sorted-key order (insurance)
        Wk  = (const float*)d_in[0];  Wo  = (const float*)d_in[1];
        Wq  = (const float*)d_in[2];  Wv  = (const float*)d_in[3];
        bek = (const float*)d_in[4];  beq = (const float*)d_in[5];
        bk  = (const float*)d_in[6];  bq  = (const float*)d_in[7];
        bv  = (const float*)d_in[8];  gk  = (const float*)d_in[9];
        gq  = (const float*)d_in[10];
        x1  = (const float*)d_in[11]; x2  = (const float*)d_in[12];
    } else {                                        // insertion order (proven)
        x1  = (const float*)d_in[0];  x2  = (const float*)d_in[1];
        Wq  = (const float*)d_in[2];  bq  = (const float*)d_in[3];
        gq  = (const float*)d_in[4];  beq = (const float*)d_in[5];
        Wk  = (const float*)d_in[6];  bk  = (const float*)d_in[7];
        gk  = (const float*)d_in[8];  bek = (const float*)d_in[9];
        Wv  = (const float*)d_in[10]; bv  = (const float*)d_in[11];
        Wo  = (const float*)d_in[12];
    }

    unsigned short* Qb = (unsigned short*)d_ws;     // 262144 ush
    unsigned short* Kb = Qb + 262144;               // 262144 ush
    unsigned short* Vf = Kb + 262144;               // 2097152 ush
    float* PART  = (float*)d_ws + 1310720;          // 3145728 fl
    float* LPART = PART + 3145728;                  // 49152 fl

    proj_all_kernel<<<1024, 256, 0, stream>>>(x1,x2,Wq,bq,gq,beq,Wk,bk,gk,bek,Wv,bv,Qb,Kb,Vf);
    attn_kernel<<<1536, 256, 0, stream>>>(Qb,Kb,Vf,PART,LPART);
    normconv_kernel<<<256, 256, 0, stream>>>(PART, LPART, Wo, (float*)d_out);
}